// Round 7
// baseline (344.166 us; speedup 1.0000x reference)
//
#include <hip/hip_runtime.h>
#include <stdint.h>

#define SEQ   2048
#define DMODEL 2048
#define NQH   32
#define NKVH  8
#define HDIM  64
#define QN    (NQH*HDIM)    // 2048
#define KVNN  (NKVH*HDIM)   // 512

typedef __bf16 bf16x8 __attribute__((ext_vector_type(8)));
typedef float  f32x4  __attribute__((ext_vector_type(4)));
typedef unsigned short u16;

__device__ __forceinline__ u16 f2bf(float f) {
  uint32_t u = __builtin_bit_cast(uint32_t, f);
  u += 0x7fffu + ((u >> 16) & 1u);   // RNE
  return (u16)(u >> 16);
}
__device__ __forceinline__ float bf2f(u16 b) {
  return __builtin_bit_cast(float, (uint32_t)b << 16);
}
__device__ __forceinline__ bool probe_is_f32(const uint32_t* p) {
  return (p[0] & 0xFFFFu) == 0u;   // cos[0]=1.0: f32->0x3F800000, bf16 pair->0x3F803F80
}

// ---------------------------------------------------------------------------
// Fused input conversion: all 7 inputs -> bf16 copies in ws (8 elts/thread).
// ---------------------------------------------------------------------------
__global__ __launch_bounds__(256)
void conv_all(const void* __restrict__ X, const void* __restrict__ cosv,
              const void* __restrict__ sinv, const void* __restrict__ wq,
              const void* __restrict__ wk, const void* __restrict__ wv,
              const void* __restrict__ wo,
              u16* __restrict__ Xc, u16* __restrict__ cosc, u16* __restrict__ sinc,
              u16* __restrict__ wqc, u16* __restrict__ wkc, u16* __restrict__ wvc,
              u16* __restrict__ woc)
{
  const bool f32in = probe_is_f32((const uint32_t*)cosv);
  const long t = (long)blockIdx.x * 256 + threadIdx.x;
  const void* src; u16* dst; long off;
  if      (t < 524288L)  { src = X;    dst = Xc;   off = t; }
  else if (t < 1048576L) { src = wq;   dst = wqc;  off = t - 524288L; }
  else if (t < 1179648L) { src = wk;   dst = wkc;  off = t - 1048576L; }
  else if (t < 1310720L) { src = wv;   dst = wvc;  off = t - 1179648L; }
  else if (t < 1835008L) { src = wo;   dst = woc;  off = t - 1310720L; }
  else if (t < 1851392L) { src = cosv; dst = cosc; off = t - 1835008L; }
  else                   { src = sinv; dst = sinc; off = t - 1851392L; }
  if (f32in) {
    const float4* s = (const float4*)src;
    float4 a = s[2*off], b = s[2*off + 1];
    union { u16 h[8]; uint4 u; } o;
    o.h[0]=f2bf(a.x); o.h[1]=f2bf(a.y); o.h[2]=f2bf(a.z); o.h[3]=f2bf(a.w);
    o.h[4]=f2bf(b.x); o.h[5]=f2bf(b.y); o.h[6]=f2bf(b.z); o.h[7]=f2bf(b.w);
    *(uint4*)(dst + off*8) = o.u;
  } else {
    *(uint4*)(dst + off*8) = ((const uint4*)src)[off];
  }
}

// ---------------------------------------------------------------------------
// Merged QKV projection, 128m x 64n tiles -> 768 blocks (3/CU).
// ---------------------------------------------------------------------------
__global__ __launch_bounds__(256, 4)
void gemm_qkv(const u16* __restrict__ A,
              const u16* __restrict__ wq, const u16* __restrict__ wk,
              const u16* __restrict__ wv,
              u16* __restrict__ Qb, u16* __restrict__ Kb, u16* __restrict__ Vb)
{
  __shared__ __align__(16) u16 As[128][40];
  __shared__ __align__(16) u16 Bs[64][40];
  const int tid  = threadIdx.x;
  const int wave = tid >> 6;
  const int lane = tid & 63;
  const int quad = lane >> 4;
  const int l16  = lane & 15;
  const int m0 = blockIdx.y * 128;
  const int n0 = blockIdx.x * 64;        // 0..3008, multiple of 64
  const int wm = (wave >> 1) * 64;
  const int wn = (wave & 1) * 32;
  const int rowA = tid >> 2;             // 0..63 (two row-groups)
  const int colA = (tid & 3) * 8;
  const int K = DMODEL;

  const u16* Bbase; u16* Cbase; int Cstride, nc0;
  if (n0 < 2048)      { Bbase = wq + (size_t)n0 * K;          Cbase = Qb; Cstride = QN;   nc0 = n0; }
  else if (n0 < 2560) { Bbase = wk + (size_t)(n0 - 2048) * K; Cbase = Kb; Cstride = KVNN; nc0 = n0 - 2048; }
  else                { Bbase = wv + (size_t)(n0 - 2560) * K; Cbase = Vb; Cstride = KVNN; nc0 = n0 - 2560; }

  f32x4 acc[4][2];
  #pragma unroll
  for (int i = 0; i < 4; i++)
    #pragma unroll
    for (int j = 0; j < 2; j++)
      acc[i][j] = (f32x4){0.f, 0.f, 0.f, 0.f};

  for (int k0 = 0; k0 < K; k0 += 32) {
    uint4 a0 = *(const uint4*)(A + (size_t)(m0 + rowA)      * K + k0 + colA);
    uint4 a1 = *(const uint4*)(A + (size_t)(m0 + rowA + 64) * K + k0 + colA);
    uint4 b0 = *(const uint4*)(Bbase + (size_t)rowA * K + k0 + colA);
    __syncthreads();
    *(uint4*)&As[rowA][colA]      = a0;
    *(uint4*)&As[rowA + 64][colA] = a1;
    *(uint4*)&Bs[rowA][colA]      = b0;
    __syncthreads();
    bf16x8 af[4], bfr[2];
    #pragma unroll
    for (int i = 0; i < 4; i++) af[i]  = *(const bf16x8*)&As[wm + i*16 + l16][quad*8];
    #pragma unroll
    for (int j = 0; j < 2; j++) bfr[j] = *(const bf16x8*)&Bs[wn + j*16 + l16][quad*8];
    #pragma unroll
    for (int i = 0; i < 4; i++)
      #pragma unroll
      for (int j = 0; j < 2; j++)
        acc[i][j] = __builtin_amdgcn_mfma_f32_16x16x32_bf16(af[i], bfr[j], acc[i][j], 0, 0, 0);
  }

  #pragma unroll
  for (int i = 0; i < 4; i++) {
    const int rb = m0 + wm + i*16 + quad*4;
    #pragma unroll
    for (int j = 0; j < 2; j++) {
      const int col = nc0 + wn + j*16 + l16;
      #pragma unroll
      for (int r = 0; r < 4; r++)
        Cbase[(size_t)(rb + r) * Cstride + col] = f2bf(acc[i][j][r]);
    }
  }
}

// ---------------------------------------------------------------------------
// O-projection GEMM, 128m x 64n tiles -> 512 blocks (2/CU). f32/bf16 out.
// ---------------------------------------------------------------------------
__global__ __launch_bounds__(256, 4)
void gemm_nt(const u16* __restrict__ A, const u16* __restrict__ B,
             void* __restrict__ C, int M, int N, int K,
             const uint32_t* outprobe)
{
  __shared__ __align__(16) u16 As[128][40];
  __shared__ __align__(16) u16 Bs[64][40];
  const int tid  = threadIdx.x;
  const int wave = tid >> 6;
  const int lane = tid & 63;
  const int quad = lane >> 4;
  const int l16  = lane & 15;
  const int m0 = blockIdx.y * 128;
  const int n0 = blockIdx.x * 64;
  const int wm = (wave >> 1) * 64;
  const int wn = (wave & 1) * 32;
  const int rowA = tid >> 2;
  const int colA = (tid & 3) * 8;

  f32x4 acc[4][2];
  #pragma unroll
  for (int i = 0; i < 4; i++)
    #pragma unroll
    for (int j = 0; j < 2; j++)
      acc[i][j] = (f32x4){0.f, 0.f, 0.f, 0.f};

  for (int k0 = 0; k0 < K; k0 += 32) {
    uint4 a0 = *(const uint4*)(A + (size_t)(m0 + rowA)      * K + k0 + colA);
    uint4 a1 = *(const uint4*)(A + (size_t)(m0 + rowA + 64) * K + k0 + colA);
    uint4 b0 = *(const uint4*)(B + (size_t)(n0 + rowA) * K + k0 + colA);
    __syncthreads();
    *(uint4*)&As[rowA][colA]      = a0;
    *(uint4*)&As[rowA + 64][colA] = a1;
    *(uint4*)&Bs[rowA][colA]      = b0;
    __syncthreads();
    bf16x8 af[4], bfr[2];
    #pragma unroll
    for (int i = 0; i < 4; i++) af[i]  = *(const bf16x8*)&As[wm + i*16 + l16][quad*8];
    #pragma unroll
    for (int j = 0; j < 2; j++) bfr[j] = *(const bf16x8*)&Bs[wn + j*16 + l16][quad*8];
    #pragma unroll
    for (int i = 0; i < 4; i++)
      #pragma unroll
      for (int j = 0; j < 2; j++)
        acc[i][j] = __builtin_amdgcn_mfma_f32_16x16x32_bf16(af[i], bfr[j], acc[i][j], 0, 0, 0);
  }

  const bool f32out = (outprobe != nullptr) && probe_is_f32(outprobe);
  #pragma unroll
  for (int i = 0; i < 4; i++) {
    const int rb = m0 + wm + i*16 + quad*4;
    #pragma unroll
    for (int j = 0; j < 2; j++) {
      const int col = n0 + wn + j*16 + l16;
      if (f32out) {
        float* Cf = (float*)C;
        #pragma unroll
        for (int r = 0; r < 4; r++)
          Cf[(size_t)(rb + r) * N + col] = acc[i][j][r];
      } else {
        u16* Ch = (u16*)C;
        #pragma unroll
        for (int r = 0; r < 4; r++)
          Ch[(size_t)(rb + r) * N + col] = f2bf(acc[i][j][r]);
      }
    }
  }
}

// ---------------------------------------------------------------------------
// RoPE in-place on K only (Q rope fused into attn). [SEQ][512].
// ---------------------------------------------------------------------------
__global__ void rope_k(u16* __restrict__ Kb,
                       const u16* __restrict__ cosb, const u16* __restrict__ sinb)
{
  const int idx = blockIdx.x * 256 + threadIdx.x;   // SEQ*NKVH*32 = 524288
  const int s = idx >> 8;
  const int rem = idx & 255;
  u16* base = Kb + (size_t)s * KVNN + (rem >> 5) * 64;
  const int d = rem & 31;
  const float x1 = bf2f(base[d]);
  const float x2 = bf2f(base[d + 32]);
  const float c  = bf2f(cosb[s * 64 + d]);     // cos[d+32] == cos[d]
  const float sn = bf2f(sinb[s * 64 + d]);
  base[d]      = f2bf(x1 * c - x2 * sn);
  base[d + 32] = f2bf(x2 * c + x1 * sn);
}

// ---------------------------------------------------------------------------
// Global V transpose: Vb [SEQ][512] -> Vtg [8][64][SEQ]  (per-kvh [d][s]).
// ---------------------------------------------------------------------------
__global__ __launch_bounds__(256)
void vtrans(const u16* __restrict__ Vb, u16* __restrict__ Vtg)
{
  __shared__ __align__(16) u16 T[64][72];
  const int tid = threadIdx.x;
  const int hkv = blockIdx.x & 7;
  const int s0  = (blockIdx.x >> 3) * 64;
  const int r = tid >> 3;            // 0..31
  const int c = (tid & 7) * 8;       // 0..56
  *(uint4*)&T[r][c]      = *(const uint4*)(Vb + (size_t)(s0 + r)      * KVNN + hkv*64 + c);
  *(uint4*)&T[r + 32][c] = *(const uint4*)(Vb + (size_t)(s0 + r + 32) * KVNN + hkv*64 + c);
  __syncthreads();
  #pragma unroll
  for (int dd = 0; dd < 64; dd += 32) {
    const int d = (tid >> 3) + dd;
    union { u16 h[8]; uint4 u; } o;
    #pragma unroll
    for (int j = 0; j < 8; j++) o.h[j] = T[c + j][d];
    *(uint4*)(Vtg + (size_t)(hkv*64 + d) * SEQ + s0 + c) = o.u;
  }
}

// ---------------------------------------------------------------------------
// Causal GQA flash attention, v4: 2-wave blocks for max TLP.
// Block = (head, 32-row tile), wave = 16 rows. Grid 2048 blocks = 8/CU,
// launch_bounds(128,4) -> 16 waves/CU. K staged coalesced into LDS (cheap
// 2-wave barrier); V-frags direct from pre-transposed Vtg (L2-resident).
// Q RoPE + 1/8 scale fused into the one-time Q load. Heavy tiles first.
// ---------------------------------------------------------------------------
__device__ __forceinline__ float qmax16(float v) {
  v = fmaxf(v, __shfl_xor(v, 1)); v = fmaxf(v, __shfl_xor(v, 2));
  v = fmaxf(v, __shfl_xor(v, 4)); v = fmaxf(v, __shfl_xor(v, 8));
  return v;
}
__device__ __forceinline__ float qsum16(float v) {
  v += __shfl_xor(v, 1); v += __shfl_xor(v, 2);
  v += __shfl_xor(v, 4); v += __shfl_xor(v, 8);
  return v;
}

__global__ __launch_bounds__(128, 4)
void attn_kernel(const u16* __restrict__ Qb,   // [SEQ][2048] pre-rope
                 const u16* __restrict__ Kb,   // [SEQ][512]  RoPE'd
                 const u16* __restrict__ Vtg,  // [8][64][SEQ]
                 u16* __restrict__ Ob,         // [SEQ][2048]
                 const u16* __restrict__ cosb, const u16* __restrict__ sinb)
{
  __shared__ __align__(16) u16 Ks[64][72];     // [key][d]
  __shared__ __align__(16) u16 Ps[2][16][72];  // per-wave P round-trip
  const int tid  = threadIdx.x;
  const int wave = tid >> 6;
  const int lane = tid & 63;
  const int quad = lane >> 4;
  const int l16  = lane & 15;
  const int h    = blockIdx.x & 31;
  const int tile = 63 - (blockIdx.x >> 5);     // heavy first
  const int hkv  = h >> 2;
  const int trow0 = tile * 32 + wave * 16;     // wave's first q row
  const int ktmax = (tile >> 1) + 1;

  // ---- one-time Q load + fused RoPE + 1/8 scale (A-layout frags) ----
  bf16x8 qf[2];
  {
    const int qrow = trow0 + l16;
    const u16* qp = Qb + (size_t)qrow * QN + h*64 + quad*8;
    union { bf16x8 v; u16 h8[8]; } lo, hi, cv, sv, olo, ohi;
    lo.v = *(const bf16x8*)qp;
    hi.v = *(const bf16x8*)(qp + 32);
    cv.v = *(const bf16x8*)(cosb + qrow*64 + quad*8);   // cos[d+32]==cos[d]
    sv.v = *(const bf16x8*)(sinb + qrow*64 + quad*8);
    #pragma unroll
    for (int j = 0; j < 8; j++) {
      const float x1 = bf2f(lo.h8[j]), x2 = bf2f(hi.h8[j]);
      const float c = bf2f(cv.h8[j]), sn = bf2f(sv.h8[j]);
      olo.h8[j] = f2bf((x1*c - x2*sn) * 0.125f);
      ohi.h8[j] = f2bf((x2*c + x1*sn) * 0.125f);
    }
    qf[0] = olo.v;
    qf[1] = ohi.v;
  }

  f32x4 oacc[4];
  #pragma unroll
  for (int nt = 0; nt < 4; nt++) oacc[nt] = (f32x4){0.f, 0.f, 0.f, 0.f};
  float m_run[4], l_run[4];
  #pragma unroll
  for (int r = 0; r < 4; r++) { m_run[r] = -1e30f; l_run[r] = 0.f; }

  const int srow = tid >> 3;          // 0..15 (+16j)
  const int scol = (tid & 7) * 8;     // 0..56

  for (int kt = 0; kt < ktmax; kt++) {
    const int kb = kt * 64;
    const bool last  = (kt == ktmax - 1);
    const bool halfT = last && ((tile & 1) == 0);  // keys 32..63 dead

    // ---- stage K tile (coalesced, 4 x b128 per thread) ----
    uint4 kv[4];
    #pragma unroll
    for (int j = 0; j < 4; j++)
      kv[j] = *(const uint4*)(Kb + (size_t)(kb + srow + j*16) * KVNN + hkv*64 + scol);
    __syncthreads();
    #pragma unroll
    for (int j = 0; j < 4; j++)
      *(uint4*)&Ks[srow + j*16][scol] = kv[j];
    __syncthreads();

    // ---- V^T frags direct from global (prefetch; skip dead half) ----
    bf16x8 vf[2][4];
    #pragma unroll
    for (int ks = 0; ks < 2; ks++) {
      if (halfT && ks == 1) continue;
      #pragma unroll
      for (int nt = 0; nt < 4; nt++)
        vf[ks][nt] = *(const bf16x8*)(Vtg + (size_t)(hkv*64 + nt*16 + l16) * SEQ
                                          + kb + ks*32 + quad*8);
    }

    // ---- S = Q @ K^T ----
    f32x4 sacc[4];
    #pragma unroll
    for (int nt = 0; nt < 4; nt++) sacc[nt] = (f32x4){0.f, 0.f, 0.f, 0.f};
    #pragma unroll
    for (int ks = 0; ks < 2; ks++)
      #pragma unroll
      for (int nt = 0; nt < 4; nt++) {
        if (halfT && nt >= 2) continue;
        bf16x8 kf = *(const bf16x8*)&Ks[nt*16 + l16][ks*32 + quad*8];
        sacc[nt] = __builtin_amdgcn_mfma_f32_16x16x32_bf16(qf[ks], kf, sacc[nt], 0, 0, 0);
      }
    // ---- causal mask (last tile only) ----
    if (last) {
      #pragma unroll
      for (int nt = 0; nt < 4; nt++)
        #pragma unroll
        for (int r = 0; r < 4; r++) {
          if (halfT && nt >= 2) { sacc[nt][r] = -1e30f; continue; }
          if (kb + nt*16 + l16 > trow0 + quad*4 + r)
            sacc[nt][r] = -1e30f;
        }
    }
    // ---- online softmax ----
    float alpha[4];
    #pragma unroll
    for (int r = 0; r < 4; r++) {
      float mx = fmaxf(fmaxf(sacc[0][r], sacc[1][r]), fmaxf(sacc[2][r], sacc[3][r]));
      mx = qmax16(mx);
      const float mnew = fmaxf(m_run[r], mx);
      alpha[r] = __expf(m_run[r] - mnew);
      m_run[r] = mnew;
      float rs = 0.f;
      #pragma unroll
      for (int nt = 0; nt < 4; nt++) {
        const float p = __expf(sacc[nt][r] - mnew);
        rs += p;
        Ps[wave][quad*4 + r][nt*16 + l16] = f2bf(p);   // C-layout write
      }
      rs = qsum16(rs);
      l_run[r] = l_run[r] * alpha[r] + rs;
    }
    #pragma unroll
    for (int nt = 0; nt < 4; nt++)
      #pragma unroll
      for (int r = 0; r < 4; r++)
        oacc[nt][r] *= alpha[r];
    // keep Ps vector loads below the scalar Ps stores (wave-private, in-order)
    asm volatile("" ::: "memory");
    // ---- O += P @ V ----
    #pragma unroll
    for (int ks = 0; ks < 2; ks++) {
      if (halfT && ks == 1) continue;
      bf16x8 pf = *(const bf16x8*)&Ps[wave][l16][ks*32 + quad*8];
      #pragma unroll
      for (int nt = 0; nt < 4; nt++)
        oacc[nt] = __builtin_amdgcn_mfma_f32_16x16x32_bf16(pf, vf[ks][nt], oacc[nt], 0, 0, 0);
    }
  }

  // ---- epilogue ----
  #pragma unroll
  for (int r = 0; r < 4; r++) {
    const float inv = 1.0f / l_run[r];
    const int qrow = trow0 + quad*4 + r;
    #pragma unroll
    for (int nt = 0; nt < 4; nt++)
      Ob[(size_t)qrow * QN + h*64 + nt*16 + l16] = f2bf(oacc[nt][r] * inv);
  }
}

// ---------------------------------------------------------------------------
extern "C" void kernel_launch(void* const* d_in, const int* in_sizes, int n_in,
                              void* d_out, int out_size, void* d_ws, size_t ws_size,
                              hipStream_t stream) {
  const void* X    = d_in[0];
  const void* cosr = d_in[1];
  const void* sinr = d_in[2];
  const void* wq   = d_in[3];
  const void* wk   = d_in[4];
  const void* wv   = d_in[5];
  const void* wo   = d_in[6];

  char* ws = (char*)d_ws;
  const size_t MB = 1024u * 1024u;
  u16* Xc   = (u16*)(ws);                      // 8 MB
  u16* wqc  = (u16*)(ws + 8*MB);               // 8 MB (Ab aliases after QKV gemm)
  u16* wkc  = (u16*)(ws + 16*MB);              // 2 MB
  u16* wvc  = (u16*)(ws + 18*MB);              // 2 MB
  u16* woc  = (u16*)(ws + 20*MB);              // 8 MB
  u16* cosc = (u16*)(ws + 28*MB);              // 256 KB
  u16* sinc = (u16*)(ws + 28*MB + 256*1024);   // 256 KB
  u16* Qb   = (u16*)(ws + 28*MB + 512*1024);   // 8 MB
  u16* Kb   = (u16*)(ws + 36*MB + 512*1024);   // 2 MB
  u16* Vb   = (u16*)(ws + 38*MB + 512*1024);   // 2 MB
  u16* Vtg  = (u16*)(ws + 40*MB + 512*1024);   // 2 MB
  u16* Ab   = wqc;   // wqc dead after gemm_qkv

  dim3 blk(256);
  conv_all<<<dim3(7296), blk, 0, stream>>>(X, cosr, sinr, wq, wk, wv, wo,
                                           Xc, cosc, sinc, wqc, wkc, wvc, woc);
  gemm_qkv<<<dim3(48, 16), blk, 0, stream>>>(Xc, wqc, wkc, wvc, Qb, Kb, Vb);
  rope_k<<<dim3((SEQ*NKVH*32)/256), blk, 0, stream>>>(Kb, cosc, sinc);
  vtrans<<<dim3(256), blk, 0, stream>>>(Vb, Vtg);
  attn_kernel<<<dim3(2048), dim3(128), 0, stream>>>(Qb, Kb, Vtg, Ab, cosc, sinc);
  gemm_nt<<<dim3(32, 16), blk, 0, stream>>>(Ab, woc, d_out, SEQ, DMODEL, DMODEL,
                                            (const uint32_t*)cosr);
}

// Round 8
// 270.210 us; speedup vs baseline: 1.2737x; 1.2737x over previous
//
#include <hip/hip_runtime.h>
#include <stdint.h>

#define SEQ   2048
#define DMODEL 2048
#define NQH   32
#define NKVH  8
#define HDIM  64
#define QN    (NQH*HDIM)    // 2048
#define KVNN  (NKVH*HDIM)   // 512

typedef __bf16 bf16x8 __attribute__((ext_vector_type(8)));
typedef float  f32x4  __attribute__((ext_vector_type(4)));
typedef unsigned short u16;

__device__ __forceinline__ u16 f2bf(float f) {
  uint32_t u = __builtin_bit_cast(uint32_t, f);
  u += 0x7fffu + ((u >> 16) & 1u);   // RNE
  return (u16)(u >> 16);
}
__device__ __forceinline__ float bf2f(u16 b) {
  return __builtin_bit_cast(float, (uint32_t)b << 16);
}
__device__ __forceinline__ bool probe_is_f32(const uint32_t* p) {
  return (p[0] & 0xFFFFu) == 0u;   // cos[0]=1.0: f32->0x3F800000, bf16 pair->0x3F803F80
}

// ---------------------------------------------------------------------------
// Fused input conversion: all 7 inputs -> bf16 copies in ws (8 elts/thread).
// ---------------------------------------------------------------------------
__global__ __launch_bounds__(256)
void conv_all(const void* __restrict__ X, const void* __restrict__ cosv,
              const void* __restrict__ sinv, const void* __restrict__ wq,
              const void* __restrict__ wk, const void* __restrict__ wv,
              const void* __restrict__ wo,
              u16* __restrict__ Xc, u16* __restrict__ cosc, u16* __restrict__ sinc,
              u16* __restrict__ wqc, u16* __restrict__ wkc, u16* __restrict__ wvc,
              u16* __restrict__ woc)
{
  const bool f32in = probe_is_f32((const uint32_t*)cosv);
  const long t = (long)blockIdx.x * 256 + threadIdx.x;
  const void* src; u16* dst; long off;
  if      (t < 524288L)  { src = X;    dst = Xc;   off = t; }
  else if (t < 1048576L) { src = wq;   dst = wqc;  off = t - 524288L; }
  else if (t < 1179648L) { src = wk;   dst = wkc;  off = t - 1048576L; }
  else if (t < 1310720L) { src = wv;   dst = wvc;  off = t - 1179648L; }
  else if (t < 1835008L) { src = wo;   dst = woc;  off = t - 1310720L; }
  else if (t < 1851392L) { src = cosv; dst = cosc; off = t - 1835008L; }
  else                   { src = sinv; dst = sinc; off = t - 1851392L; }
  if (f32in) {
    const float4* s = (const float4*)src;
    float4 a = s[2*off], b = s[2*off + 1];
    union { u16 h[8]; uint4 u; } o;
    o.h[0]=f2bf(a.x); o.h[1]=f2bf(a.y); o.h[2]=f2bf(a.z); o.h[3]=f2bf(a.w);
    o.h[4]=f2bf(b.x); o.h[5]=f2bf(b.y); o.h[6]=f2bf(b.z); o.h[7]=f2bf(b.w);
    *(uint4*)(dst + off*8) = o.u;
  } else {
    *(uint4*)(dst + off*8) = ((const uint4*)src)[off];
  }
}

// ---------------------------------------------------------------------------
// Merged QKV projection: C = X @ [Wq;Wk;Wv]^T over N=3072, 128x128 tiles.
// (round-5 config — best measured)
// ---------------------------------------------------------------------------
__global__ __launch_bounds__(256, 2)
void gemm_qkv(const u16* __restrict__ A,
              const u16* __restrict__ wq, const u16* __restrict__ wk,
              const u16* __restrict__ wv,
              u16* __restrict__ Qb, u16* __restrict__ Kb, u16* __restrict__ Vb)
{
  __shared__ __align__(16) u16 As[128][40];
  __shared__ __align__(16) u16 Bs[128][40];
  const int tid  = threadIdx.x;
  const int wave = tid >> 6;
  const int lane = tid & 63;
  const int quad = lane >> 4;
  const int l16  = lane & 15;
  const int m0 = blockIdx.y * 128;
  const int n0 = blockIdx.x * 128;
  const int wm = (wave >> 1) * 64;
  const int wn = (wave & 1) * 64;
  const int srow = tid >> 2;
  const int scol = (tid & 3) * 8;
  const int K = DMODEL;

  const u16* Bbase; u16* Cbase; int Cstride, nc0;
  if (n0 < 2048)      { Bbase = wq + (size_t)n0 * K;          Cbase = Qb; Cstride = QN;   nc0 = n0; }
  else if (n0 < 2560) { Bbase = wk + (size_t)(n0 - 2048) * K; Cbase = Kb; Cstride = KVNN; nc0 = n0 - 2048; }
  else                { Bbase = wv + (size_t)(n0 - 2560) * K; Cbase = Vb; Cstride = KVNN; nc0 = n0 - 2560; }

  f32x4 acc[4][4];
  #pragma unroll
  for (int i = 0; i < 4; i++)
    #pragma unroll
    for (int j = 0; j < 4; j++)
      acc[i][j] = (f32x4){0.f, 0.f, 0.f, 0.f};

  for (int k0 = 0; k0 < K; k0 += 32) {
    uint4 a0 = *(const uint4*)(A + (size_t)(m0 + srow)      * K + k0 + scol);
    uint4 a1 = *(const uint4*)(A + (size_t)(m0 + srow + 64) * K + k0 + scol);
    uint4 b0 = *(const uint4*)(Bbase + (size_t)(srow)      * K + k0 + scol);
    uint4 b1 = *(const uint4*)(Bbase + (size_t)(srow + 64) * K + k0 + scol);
    __syncthreads();
    *(uint4*)&As[srow][scol]      = a0;
    *(uint4*)&As[srow + 64][scol] = a1;
    *(uint4*)&Bs[srow][scol]      = b0;
    *(uint4*)&Bs[srow + 64][scol] = b1;
    __syncthreads();
    bf16x8 af[4], bfr[4];
    #pragma unroll
    for (int i = 0; i < 4; i++) af[i]  = *(const bf16x8*)&As[wm + i*16 + l16][quad*8];
    #pragma unroll
    for (int j = 0; j < 4; j++) bfr[j] = *(const bf16x8*)&Bs[wn + j*16 + l16][quad*8];
    #pragma unroll
    for (int i = 0; i < 4; i++)
      #pragma unroll
      for (int j = 0; j < 4; j++)
        acc[i][j] = __builtin_amdgcn_mfma_f32_16x16x32_bf16(af[i], bfr[j], acc[i][j], 0, 0, 0);
  }

  #pragma unroll
  for (int i = 0; i < 4; i++) {
    const int rb = m0 + wm + i*16 + quad*4;
    #pragma unroll
    for (int j = 0; j < 4; j++) {
      const int col = nc0 + wn + j*16 + l16;
      #pragma unroll
      for (int r = 0; r < 4; r++)
        Cbase[(size_t)(rb + r) * Cstride + col] = f2bf(acc[i][j][r]);
    }
  }
}

// ---------------------------------------------------------------------------
// O-projection GEMM, 128x128 tiles (round-5 config). f32/bf16 out per probe.
// ---------------------------------------------------------------------------
__global__ __launch_bounds__(256, 2)
void gemm_nt(const u16* __restrict__ A, const u16* __restrict__ B,
             void* __restrict__ C, int M, int N, int K,
             const uint32_t* outprobe)
{
  __shared__ __align__(16) u16 As[128][40];
  __shared__ __align__(16) u16 Bs[128][40];
  const int tid  = threadIdx.x;
  const int wave = tid >> 6;
  const int lane = tid & 63;
  const int quad = lane >> 4;
  const int l16  = lane & 15;
  const int m0 = blockIdx.y * 128;
  const int n0 = blockIdx.x * 128;
  const int wm = (wave >> 1) * 64;
  const int wn = (wave & 1) * 64;
  const int srow = tid >> 2;
  const int scol = (tid & 3) * 8;

  f32x4 acc[4][4];
  #pragma unroll
  for (int i = 0; i < 4; i++)
    #pragma unroll
    for (int j = 0; j < 4; j++)
      acc[i][j] = (f32x4){0.f, 0.f, 0.f, 0.f};

  for (int k0 = 0; k0 < K; k0 += 32) {
    uint4 a0 = *(const uint4*)(A + (size_t)(m0 + srow)      * K + k0 + scol);
    uint4 a1 = *(const uint4*)(A + (size_t)(m0 + srow + 64) * K + k0 + scol);
    uint4 b0 = *(const uint4*)(B + (size_t)(n0 + srow)      * K + k0 + scol);
    uint4 b1 = *(const uint4*)(B + (size_t)(n0 + srow + 64) * K + k0 + scol);
    __syncthreads();
    *(uint4*)&As[srow][scol]      = a0;
    *(uint4*)&As[srow + 64][scol] = a1;
    *(uint4*)&Bs[srow][scol]      = b0;
    *(uint4*)&Bs[srow + 64][scol] = b1;
    __syncthreads();
    bf16x8 af[4], bfr[4];
    #pragma unroll
    for (int i = 0; i < 4; i++) af[i]  = *(const bf16x8*)&As[wm + i*16 + l16][quad*8];
    #pragma unroll
    for (int j = 0; j < 4; j++) bfr[j] = *(const bf16x8*)&Bs[wn + j*16 + l16][quad*8];
    #pragma unroll
    for (int i = 0; i < 4; i++)
      #pragma unroll
      for (int j = 0; j < 4; j++)
        acc[i][j] = __builtin_amdgcn_mfma_f32_16x16x32_bf16(af[i], bfr[j], acc[i][j], 0, 0, 0);
  }

  const bool f32out = (outprobe != nullptr) && probe_is_f32(outprobe);
  #pragma unroll
  for (int i = 0; i < 4; i++) {
    const int rb = m0 + wm + i*16 + quad*4;
    #pragma unroll
    for (int j = 0; j < 4; j++) {
      const int col = n0 + wn + j*16 + l16;
      if (f32out) {
        float* Cf = (float*)C;
        #pragma unroll
        for (int r = 0; r < 4; r++)
          Cf[(size_t)(rb + r) * N + col] = acc[i][j][r];
      } else {
        u16* Ch = (u16*)C;
        #pragma unroll
        for (int r = 0; r < 4; r++)
          Ch[(size_t)(rb + r) * N + col] = f2bf(acc[i][j][r]);
      }
    }
  }
}

// ---------------------------------------------------------------------------
// RoPE in-place on K only (Q rope fused into attn). [SEQ][512].
// ---------------------------------------------------------------------------
__global__ void rope_k(u16* __restrict__ Kb,
                       const u16* __restrict__ cosb, const u16* __restrict__ sinb)
{
  const int idx = blockIdx.x * 256 + threadIdx.x;   // SEQ*NKVH*32 = 524288
  const int s = idx >> 8;
  const int rem = idx & 255;
  u16* base = Kb + (size_t)s * KVNN + (rem >> 5) * 64;
  const int d = rem & 31;
  const float x1 = bf2f(base[d]);
  const float x2 = bf2f(base[d + 32]);
  const float c  = bf2f(cosb[s * 64 + d]);     // cos[d+32] == cos[d]
  const float sn = bf2f(sinb[s * 64 + d]);
  base[d]      = f2bf(x1 * c - x2 * sn);
  base[d + 32] = f2bf(x2 * c + x1 * sn);
}

// ---------------------------------------------------------------------------
// Global V transpose: Vb [SEQ][512] -> Vtg [8][64][SEQ]  (per-kvh [d][s]).
// ---------------------------------------------------------------------------
__global__ __launch_bounds__(256)
void vtrans(const u16* __restrict__ Vb, u16* __restrict__ Vtg)
{
  __shared__ __align__(16) u16 T[64][72];
  const int tid = threadIdx.x;
  const int hkv = blockIdx.x & 7;
  const int s0  = (blockIdx.x >> 3) * 64;
  const int r = tid >> 3;            // 0..31
  const int c = (tid & 7) * 8;       // 0..56
  *(uint4*)&T[r][c]      = *(const uint4*)(Vb + (size_t)(s0 + r)      * KVNN + hkv*64 + c);
  *(uint4*)&T[r + 32][c] = *(const uint4*)(Vb + (size_t)(s0 + r + 32) * KVNN + hkv*64 + c);
  __syncthreads();
  #pragma unroll
  for (int dd = 0; dd < 64; dd += 32) {
    const int d = (tid >> 3) + dd;
    union { u16 h[8]; uint4 u; } o;
    #pragma unroll
    for (int j = 0; j < 8; j++) o.h[j] = T[c + j][d];
    *(uint4*)(Vtg + (size_t)(hkv*64 + d) * SEQ + s0 + c) = o.u;
  }
}

// ---------------------------------------------------------------------------
// Causal GQA flash attention v5 = v2 structure (best measured, 98us) plus:
//  - heavy-first tile order (kills tail imbalance, v2's 22% occupancy)
//  - V pre-transposed globally; staged to LDS with coalesced b128 (no
//    in-kernel scalar transpose -> conflicts & VALU drop)
//  - 1-iteration register prefetch of K/V staging loads (latency hidden
//    behind compute; +16 VGPRs, safely under the 128 cap of bounds(256,4))
//  - Q RoPE + 1/8 scale fused into the one-time Q-frag load
// ---------------------------------------------------------------------------
__device__ __forceinline__ float qmax16(float v) {
  v = fmaxf(v, __shfl_xor(v, 1)); v = fmaxf(v, __shfl_xor(v, 2));
  v = fmaxf(v, __shfl_xor(v, 4)); v = fmaxf(v, __shfl_xor(v, 8));
  return v;
}
__device__ __forceinline__ float qsum16(float v) {
  v += __shfl_xor(v, 1); v += __shfl_xor(v, 2);
  v += __shfl_xor(v, 4); v += __shfl_xor(v, 8);
  return v;
}

__global__ __launch_bounds__(256, 4)
void attn_kernel(const u16* __restrict__ Qb,   // [SEQ][2048] pre-rope
                 const u16* __restrict__ Kb,   // [SEQ][512]  RoPE'd
                 const u16* __restrict__ Vtg,  // [8][64][SEQ]
                 u16* __restrict__ Ob,         // [SEQ][2048]
                 const u16* __restrict__ cosb, const u16* __restrict__ sinb)
{
  __shared__ __align__(16) u16 Ks[64][72];     // [key][d]
  __shared__ __align__(16) u16 Vt[64][72];     // [d][key]
  __shared__ __align__(16) u16 Ps[4][16][72];  // per-wave P round-trip

  const int tid  = threadIdx.x;
  const int wave = tid >> 6;
  const int lane = tid & 63;
  const int quad = lane >> 4;
  const int l16  = lane & 15;
  const int h    = blockIdx.x;                 // 0..31
  const int qt   = 31 - blockIdx.y;            // heavy 64-row tiles first
  const int hkv  = h >> 2;
  const int qrow0 = qt * 64 + wave * 16;
  const int ktmax = qt + 1;

  // ---- one-time Q load + fused RoPE + 1/8 scale (A-layout frags) ----
  bf16x8 qf[2];
  {
    const int qrow = qrow0 + l16;
    const u16* qp = Qb + (size_t)qrow * QN + h*64 + quad*8;
    union { bf16x8 v; u16 h8[8]; } lo, hi, cv, sv, olo, ohi;
    lo.v = *(const bf16x8*)qp;
    hi.v = *(const bf16x8*)(qp + 32);
    cv.v = *(const bf16x8*)(cosb + qrow*64 + quad*8);   // cos[d+32]==cos[d]
    sv.v = *(const bf16x8*)(sinb + qrow*64 + quad*8);
    #pragma unroll
    for (int j = 0; j < 8; j++) {
      const float x1 = bf2f(lo.h8[j]), x2 = bf2f(hi.h8[j]);
      const float c = bf2f(cv.h8[j]), sn = bf2f(sv.h8[j]);
      olo.h8[j] = f2bf((x1*c - x2*sn) * 0.125f);
      ohi.h8[j] = f2bf((x2*c + x1*sn) * 0.125f);
    }
    qf[0] = olo.v;
    qf[1] = ohi.v;
  }

  f32x4 oacc[4];
  #pragma unroll
  for (int nt = 0; nt < 4; nt++) oacc[nt] = (f32x4){0.f, 0.f, 0.f, 0.f};
  float m_run[4], l_run[4];
  #pragma unroll
  for (int r = 0; r < 4; r++) { m_run[r] = -1e30f; l_run[r] = 0.f; }

  const int sr = tid >> 3;          // 0..31
  const int sc = (tid & 7) * 8;     // 0..56

  // ---- register prefetch of tile 0 ----
  uint4 k0, k1, v0, v1;
  {
    k0 = *(const uint4*)(Kb + (size_t)(sr)      * KVNN + hkv*64 + sc);
    k1 = *(const uint4*)(Kb + (size_t)(sr + 32) * KVNN + hkv*64 + sc);
    v0 = *(const uint4*)(Vtg + (size_t)(hkv*64 + sr)      * SEQ + sc);
    v1 = *(const uint4*)(Vtg + (size_t)(hkv*64 + sr + 32) * SEQ + sc);
  }

  for (int kt = 0; kt < ktmax; kt++) {
    const int kb = kt * 64;
    const bool diag = (kt == qt);

    __syncthreads();                 // all waves done reading LDS (prev iter)
    *(uint4*)&Ks[sr][sc]      = k0;
    *(uint4*)&Ks[sr + 32][sc] = k1;
    *(uint4*)&Vt[sr][sc]      = v0;  // Vt row = d, col = key (pre-transposed)
    *(uint4*)&Vt[sr + 32][sc] = v1;
    __syncthreads();

    // ---- issue next tile's staging loads (latency hides behind compute) ----
    if (kt + 1 < ktmax) {
      const int kn = kb + 64;
      k0 = *(const uint4*)(Kb + (size_t)(kn + sr)      * KVNN + hkv*64 + sc);
      k1 = *(const uint4*)(Kb + (size_t)(kn + sr + 32) * KVNN + hkv*64 + sc);
      v0 = *(const uint4*)(Vtg + (size_t)(hkv*64 + sr)      * SEQ + kn + sc);
      v1 = *(const uint4*)(Vtg + (size_t)(hkv*64 + sr + 32) * SEQ + kn + sc);
    }

    // ---- S = Q @ K^T (skip fully-masked nt tiles on the diagonal) ----
    f32x4 sacc[4];
    #pragma unroll
    for (int nt = 0; nt < 4; nt++) sacc[nt] = (f32x4){0.f, 0.f, 0.f, 0.f};
    #pragma unroll
    for (int ks = 0; ks < 2; ks++)
      #pragma unroll
      for (int nt = 0; nt < 4; nt++)
        if (!diag || nt <= wave) {
          bf16x8 kf = *(const bf16x8*)&Ks[nt*16 + l16][ks*32 + quad*8];
          sacc[nt] = __builtin_amdgcn_mfma_f32_16x16x32_bf16(qf[ks], kf, sacc[nt], 0, 0, 0);
        }
    // ---- causal mask (diagonal tile only) ----
    if (diag) {
      #pragma unroll
      for (int nt = 0; nt < 4; nt++)
        #pragma unroll
        for (int r = 0; r < 4; r++)
          if (kb + nt*16 + l16 > qrow0 + quad*4 + r)
            sacc[nt][r] = -1e30f;
    }
    // ---- online softmax ----
    float alpha[4];
    #pragma unroll
    for (int r = 0; r < 4; r++) {
      float mx = fmaxf(fmaxf(sacc[0][r], sacc[1][r]), fmaxf(sacc[2][r], sacc[3][r]));
      mx = qmax16(mx);
      const float mnew = fmaxf(m_run[r], mx);
      alpha[r] = __expf(m_run[r] - mnew);
      m_run[r] = mnew;
      float rs = 0.f;
      #pragma unroll
      for (int nt = 0; nt < 4; nt++) {
        const float p = __expf(sacc[nt][r] - mnew);
        rs += p;
        Ps[wave][quad*4 + r][nt*16 + l16] = f2bf(p);   // C-layout write
      }
      rs = qsum16(rs);
      l_run[r] = l_run[r] * alpha[r] + rs;
    }
    #pragma unroll
    for (int nt = 0; nt < 4; nt++)
      #pragma unroll
      for (int r = 0; r < 4; r++)
        oacc[nt][r] *= alpha[r];
    // keep Ps vector loads below the scalar Ps stores (wave-private, in-order)
    asm volatile("" ::: "memory");
    // ---- O += P @ V (skip dead key-halves on the diagonal) ----
    #pragma unroll
    for (int ks = 0; ks < 2; ks++) {
      if (diag && wave < 2 && ks == 1) continue;  // keys 32..63 fully masked
      bf16x8 pf = *(const bf16x8*)&Ps[wave][l16][ks*32 + quad*8];
      #pragma unroll
      for (int nt = 0; nt < 4; nt++) {
        bf16x8 vf = *(const bf16x8*)&Vt[nt*16 + l16][ks*32 + quad*8];
        oacc[nt] = __builtin_amdgcn_mfma_f32_16x16x32_bf16(pf, vf, oacc[nt], 0, 0, 0);
      }
    }
  }

  // ---- epilogue ----
  #pragma unroll
  for (int r = 0; r < 4; r++) {
    const float inv = 1.0f / l_run[r];
    const int qrow = qrow0 + quad*4 + r;
    #pragma unroll
    for (int nt = 0; nt < 4; nt++)
      Ob[(size_t)qrow * QN + h*64 + nt*16 + l16] = f2bf(oacc[nt][r] * inv);
  }
}

// ---------------------------------------------------------------------------
extern "C" void kernel_launch(void* const* d_in, const int* in_sizes, int n_in,
                              void* d_out, int out_size, void* d_ws, size_t ws_size,
                              hipStream_t stream) {
  const void* X    = d_in[0];
  const void* cosr = d_in[1];
  const void* sinr = d_in[2];
  const void* wq   = d_in[3];
  const void* wk   = d_in[4];
  const void* wv   = d_in[5];
  const void* wo   = d_in[6];

  char* ws = (char*)d_ws;
  const size_t MB = 1024u * 1024u;
  u16* Xc   = (u16*)(ws);                      // 8 MB
  u16* wqc  = (u16*)(ws + 8*MB);               // 8 MB (Ab aliases after QKV gemm)
  u16* wkc  = (u16*)(ws + 16*MB);              // 2 MB
  u16* wvc  = (u16*)(ws + 18*MB);              // 2 MB
  u16* woc  = (u16*)(ws + 20*MB);              // 8 MB
  u16* cosc = (u16*)(ws + 28*MB);              // 256 KB
  u16* sinc = (u16*)(ws + 28*MB + 256*1024);   // 256 KB
  u16* Qb   = (u16*)(ws + 28*MB + 512*1024);   // 8 MB
  u16* Kb   = (u16*)(ws + 36*MB + 512*1024);   // 2 MB
  u16* Vb   = (u16*)(ws + 38*MB + 512*1024);   // 2 MB
  u16* Vtg  = (u16*)(ws + 40*MB + 512*1024);   // 2 MB
  u16* Ab   = wqc;   // wqc dead after gemm_qkv

  dim3 blk(256);
  conv_all<<<dim3(7296), blk, 0, stream>>>(X, cosr, sinr, wq, wk, wv, wo,
                                           Xc, cosc, sinc, wqc, wkc, wvc, woc);
  gemm_qkv<<<dim3(24, 16), blk, 0, stream>>>(Xc, wqc, wkc, wvc, Qb, Kb, Vb);
  rope_k<<<dim3((SEQ*NKVH*32)/256), blk, 0, stream>>>(Kb, cosc, sinc);
  vtrans<<<dim3(256), blk, 0, stream>>>(Vb, Vtg);
  attn_kernel<<<dim3(NQH, SEQ/64), blk, 0, stream>>>(Qb, Kb, Vtg, Ab, cosc, sinc);
  gemm_nt<<<dim3(16, 16), blk, 0, stream>>>(Ab, woc, d_out, SEQ, DMODEL, DMODEL,
                                            (const uint32_t*)cosr);
}

// Round 9
// 258.947 us; speedup vs baseline: 1.3291x; 1.0435x over previous
//
#include <hip/hip_runtime.h>
#include <stdint.h>

#define SEQ   2048
#define DMODEL 2048
#define NQH   32
#define NKVH  8
#define HDIM  64
#define QN    (NQH*HDIM)    // 2048
#define KVNN  (NKVH*HDIM)   // 512

typedef __bf16 bf16x8 __attribute__((ext_vector_type(8)));
typedef float  f32x4  __attribute__((ext_vector_type(4)));
typedef unsigned short u16;

__device__ __forceinline__ u16 f2bf(float f) {
  uint32_t u = __builtin_bit_cast(uint32_t, f);
  u += 0x7fffu + ((u >> 16) & 1u);   // RNE
  return (u16)(u >> 16);
}
__device__ __forceinline__ float bf2f(u16 b) {
  return __builtin_bit_cast(float, (uint32_t)b << 16);
}
__device__ __forceinline__ bool probe_is_f32(const uint32_t* p) {
  return (p[0] & 0xFFFFu) == 0u;   // cos[0]=1.0: f32->0x3F800000, bf16 pair->0x3F803F80
}

// global -> LDS direct DMA, 16B per lane, LDS dest = uniform base + lane*16
__device__ __forceinline__ void glds16(const u16* g, void* lds) {
  __builtin_amdgcn_global_load_lds(
      (const __attribute__((address_space(1))) uint32_t*)g,
      (__attribute__((address_space(3))) uint32_t*)lds, 16, 0, 0);
}

// ---------------------------------------------------------------------------
// Fused input conversion: all 7 inputs -> bf16 copies in ws (8 elts/thread).
// ---------------------------------------------------------------------------
__global__ __launch_bounds__(256)
void conv_all(const void* __restrict__ X, const void* __restrict__ cosv,
              const void* __restrict__ sinv, const void* __restrict__ wq,
              const void* __restrict__ wk, const void* __restrict__ wv,
              const void* __restrict__ wo,
              u16* __restrict__ Xc, u16* __restrict__ cosc, u16* __restrict__ sinc,
              u16* __restrict__ wqc, u16* __restrict__ wkc, u16* __restrict__ wvc,
              u16* __restrict__ woc)
{
  const bool f32in = probe_is_f32((const uint32_t*)cosv);
  const long t = (long)blockIdx.x * 256 + threadIdx.x;
  const void* src; u16* dst; long off;
  if      (t < 524288L)  { src = X;    dst = Xc;   off = t; }
  else if (t < 1048576L) { src = wq;   dst = wqc;  off = t - 524288L; }
  else if (t < 1179648L) { src = wk;   dst = wkc;  off = t - 1048576L; }
  else if (t < 1310720L) { src = wv;   dst = wvc;  off = t - 1179648L; }
  else if (t < 1835008L) { src = wo;   dst = woc;  off = t - 1310720L; }
  else if (t < 1851392L) { src = cosv; dst = cosc; off = t - 1835008L; }
  else                   { src = sinv; dst = sinc; off = t - 1851392L; }
  if (f32in) {
    const float4* s = (const float4*)src;
    float4 a = s[2*off], b = s[2*off + 1];
    union { u16 h[8]; uint4 u; } o;
    o.h[0]=f2bf(a.x); o.h[1]=f2bf(a.y); o.h[2]=f2bf(a.z); o.h[3]=f2bf(a.w);
    o.h[4]=f2bf(b.x); o.h[5]=f2bf(b.y); o.h[6]=f2bf(b.z); o.h[7]=f2bf(b.w);
    *(uint4*)(dst + off*8) = o.u;
  } else {
    *(uint4*)(dst + off*8) = ((const uint4*)src)[off];
  }
}

// ---------------------------------------------------------------------------
// Merged QKV projection, 64m x 128n tiles, global_load_lds staging (m97).
// Grid 24 x 32 = 768 blocks (3/CU). Unpadded LDS (glds requires contiguity).
// ---------------------------------------------------------------------------
__global__ __launch_bounds__(256, 4)
void gemm_qkv(const u16* __restrict__ A,
              const u16* __restrict__ wq, const u16* __restrict__ wk,
              const u16* __restrict__ wv,
              u16* __restrict__ Qb, u16* __restrict__ Kb, u16* __restrict__ Vb)
{
  __shared__ __align__(16) u16 As[64][32];     // 4 KB, rows contiguous
  __shared__ __align__(16) u16 Bs[128][32];    // 8 KB
  const int tid  = threadIdx.x;
  const int wave = tid >> 6;
  const int lane = tid & 63;
  const int quad = lane >> 4;
  const int l16  = lane & 15;
  const int m0 = blockIdx.y * 64;
  const int n0 = blockIdx.x * 128;
  const int wm = (wave & 1) * 32;
  const int wn = (wave >> 1) * 64;
  const int K = DMODEL;
  const int lr = lane >> 2;          // 0..15 row within chunk
  const int lc = (lane & 3) * 8;     // elem col within 32

  const u16* Bbase; u16* Cbase; int Cstride, nc0;
  if (n0 < 2048)      { Bbase = wq + (size_t)n0 * K;          Cbase = Qb; Cstride = QN;   nc0 = n0; }
  else if (n0 < 2560) { Bbase = wk + (size_t)(n0 - 2048) * K; Cbase = Kb; Cstride = KVNN; nc0 = n0 - 2048; }
  else                { Bbase = wv + (size_t)(n0 - 2560) * K; Cbase = Vb; Cstride = KVNN; nc0 = n0 - 2560; }

  f32x4 acc[2][4];
  #pragma unroll
  for (int i = 0; i < 2; i++)
    #pragma unroll
    for (int j = 0; j < 4; j++)
      acc[i][j] = (f32x4){0.f, 0.f, 0.f, 0.f};

  for (int k0 = 0; k0 < K; k0 += 32) {
    __syncthreads();   // prev iter's fragment reads done before DMA overwrites
    // wave w stages: A chunk w (rows 16w..16w+15), B chunks w and w+4
    glds16(A + (size_t)(m0 + 16*wave + lr) * K + k0 + lc,
           (char*)&As[0][0] + wave*1024);
    glds16(Bbase + (size_t)(16*wave + lr) * K + k0 + lc,
           (char*)&Bs[0][0] + wave*1024);
    glds16(Bbase + (size_t)(64 + 16*wave + lr) * K + k0 + lc,
           (char*)&Bs[0][0] + (4+wave)*1024);
    __syncthreads();   // vmcnt(0) drain -> DMA complete
    bf16x8 af[2], bfr[4];
    #pragma unroll
    for (int i = 0; i < 2; i++) af[i]  = *(const bf16x8*)&As[wm + i*16 + l16][quad*8];
    #pragma unroll
    for (int j = 0; j < 4; j++) bfr[j] = *(const bf16x8*)&Bs[wn + j*16 + l16][quad*8];
    #pragma unroll
    for (int i = 0; i < 2; i++)
      #pragma unroll
      for (int j = 0; j < 4; j++)
        acc[i][j] = __builtin_amdgcn_mfma_f32_16x16x32_bf16(af[i], bfr[j], acc[i][j], 0, 0, 0);
  }

  #pragma unroll
  for (int i = 0; i < 2; i++) {
    const int rb = m0 + wm + i*16 + quad*4;
    #pragma unroll
    for (int j = 0; j < 4; j++) {
      const int col = nc0 + wn + j*16 + l16;
      #pragma unroll
      for (int r = 0; r < 4; r++)
        Cbase[(size_t)(rb + r) * Cstride + col] = f2bf(acc[i][j][r]);
    }
  }
}

// ---------------------------------------------------------------------------
// O-projection GEMM, 64m x 128n tiles + global_load_lds. Grid 16 x 32 = 512.
// ---------------------------------------------------------------------------
__global__ __launch_bounds__(256, 4)
void gemm_nt(const u16* __restrict__ A, const u16* __restrict__ B,
             void* __restrict__ C, int M, int N, int K,
             const uint32_t* outprobe)
{
  __shared__ __align__(16) u16 As[64][32];
  __shared__ __align__(16) u16 Bs[128][32];
  const int tid  = threadIdx.x;
  const int wave = tid >> 6;
  const int lane = tid & 63;
  const int quad = lane >> 4;
  const int l16  = lane & 15;
  const int m0 = blockIdx.y * 64;
  const int n0 = blockIdx.x * 128;
  const int wm = (wave & 1) * 32;
  const int wn = (wave >> 1) * 64;
  const int lr = lane >> 2;
  const int lc = (lane & 3) * 8;

  f32x4 acc[2][4];
  #pragma unroll
  for (int i = 0; i < 2; i++)
    #pragma unroll
    for (int j = 0; j < 4; j++)
      acc[i][j] = (f32x4){0.f, 0.f, 0.f, 0.f};

  for (int k0 = 0; k0 < K; k0 += 32) {
    __syncthreads();
    glds16(A + (size_t)(m0 + 16*wave + lr) * K + k0 + lc,
           (char*)&As[0][0] + wave*1024);
    glds16(B + (size_t)(n0 + 16*wave + lr) * K + k0 + lc,
           (char*)&Bs[0][0] + wave*1024);
    glds16(B + (size_t)(n0 + 64 + 16*wave + lr) * K + k0 + lc,
           (char*)&Bs[0][0] + (4+wave)*1024);
    __syncthreads();
    bf16x8 af[2], bfr[4];
    #pragma unroll
    for (int i = 0; i < 2; i++) af[i]  = *(const bf16x8*)&As[wm + i*16 + l16][quad*8];
    #pragma unroll
    for (int j = 0; j < 4; j++) bfr[j] = *(const bf16x8*)&Bs[wn + j*16 + l16][quad*8];
    #pragma unroll
    for (int i = 0; i < 2; i++)
      #pragma unroll
      for (int j = 0; j < 4; j++)
        acc[i][j] = __builtin_amdgcn_mfma_f32_16x16x32_bf16(af[i], bfr[j], acc[i][j], 0, 0, 0);
  }

  const bool f32out = (outprobe != nullptr) && probe_is_f32(outprobe);
  #pragma unroll
  for (int i = 0; i < 2; i++) {
    const int rb = m0 + wm + i*16 + quad*4;
    #pragma unroll
    for (int j = 0; j < 4; j++) {
      const int col = n0 + wn + j*16 + l16;
      if (f32out) {
        float* Cf = (float*)C;
        #pragma unroll
        for (int r = 0; r < 4; r++)
          Cf[(size_t)(rb + r) * N + col] = acc[i][j][r];
      } else {
        u16* Ch = (u16*)C;
        #pragma unroll
        for (int r = 0; r < 4; r++)
          Ch[(size_t)(rb + r) * N + col] = f2bf(acc[i][j][r]);
      }
    }
  }
}

// ---------------------------------------------------------------------------
// RoPE in-place on K only (Q rope fused into attn). [SEQ][512].
// ---------------------------------------------------------------------------
__global__ void rope_k(u16* __restrict__ Kb,
                       const u16* __restrict__ cosb, const u16* __restrict__ sinb)
{
  const int idx = blockIdx.x * 256 + threadIdx.x;   // SEQ*NKVH*32 = 524288
  const int s = idx >> 8;
  const int rem = idx & 255;
  u16* base = Kb + (size_t)s * KVNN + (rem >> 5) * 64;
  const int d = rem & 31;
  const float x1 = bf2f(base[d]);
  const float x2 = bf2f(base[d + 32]);
  const float c  = bf2f(cosb[s * 64 + d]);     // cos[d+32] == cos[d]
  const float sn = bf2f(sinb[s * 64 + d]);
  base[d]      = f2bf(x1 * c - x2 * sn);
  base[d + 32] = f2bf(x2 * c + x1 * sn);
}

// ---------------------------------------------------------------------------
// Global V transpose: Vb [SEQ][512] -> Vtg [8][64][SEQ]  (per-kvh [d][s]).
// ---------------------------------------------------------------------------
__global__ __launch_bounds__(256)
void vtrans(const u16* __restrict__ Vb, u16* __restrict__ Vtg)
{
  __shared__ __align__(16) u16 T[64][72];
  const int tid = threadIdx.x;
  const int hkv = blockIdx.x & 7;
  const int s0  = (blockIdx.x >> 3) * 64;
  const int r = tid >> 3;            // 0..31
  const int c = (tid & 7) * 8;       // 0..56
  *(uint4*)&T[r][c]      = *(const uint4*)(Vb + (size_t)(s0 + r)      * KVNN + hkv*64 + c);
  *(uint4*)&T[r + 32][c] = *(const uint4*)(Vb + (size_t)(s0 + r + 32) * KVNN + hkv*64 + c);
  __syncthreads();
  #pragma unroll
  for (int dd = 0; dd < 64; dd += 32) {
    const int d = (tid >> 3) + dd;
    union { u16 h[8]; uint4 u; } o;
    #pragma unroll
    for (int j = 0; j < 8; j++) o.h[j] = T[c + j][d];
    *(uint4*)(Vtg + (size_t)(hkv*64 + d) * SEQ + s0 + c) = o.u;
  }
}

// ---------------------------------------------------------------------------
// Causal GQA flash attention v5 (round-8 best: 86us). Unchanged this round.
// ---------------------------------------------------------------------------
__device__ __forceinline__ float qmax16(float v) {
  v = fmaxf(v, __shfl_xor(v, 1)); v = fmaxf(v, __shfl_xor(v, 2));
  v = fmaxf(v, __shfl_xor(v, 4)); v = fmaxf(v, __shfl_xor(v, 8));
  return v;
}
__device__ __forceinline__ float qsum16(float v) {
  v += __shfl_xor(v, 1); v += __shfl_xor(v, 2);
  v += __shfl_xor(v, 4); v += __shfl_xor(v, 8);
  return v;
}

__global__ __launch_bounds__(256, 4)
void attn_kernel(const u16* __restrict__ Qb,   // [SEQ][2048] pre-rope
                 const u16* __restrict__ Kb,   // [SEQ][512]  RoPE'd
                 const u16* __restrict__ Vtg,  // [8][64][SEQ]
                 u16* __restrict__ Ob,         // [SEQ][2048]
                 const u16* __restrict__ cosb, const u16* __restrict__ sinb)
{
  __shared__ __align__(16) u16 Ks[64][72];     // [key][d]
  __shared__ __align__(16) u16 Vt[64][72];     // [d][key]
  __shared__ __align__(16) u16 Ps[4][16][72];  // per-wave P round-trip

  const int tid  = threadIdx.x;
  const int wave = tid >> 6;
  const int lane = tid & 63;
  const int quad = lane >> 4;
  const int l16  = lane & 15;
  const int h    = blockIdx.x;                 // 0..31
  const int qt   = 31 - blockIdx.y;            // heavy 64-row tiles first
  const int hkv  = h >> 2;
  const int qrow0 = qt * 64 + wave * 16;
  const int ktmax = qt + 1;

  // ---- one-time Q load + fused RoPE + 1/8 scale (A-layout frags) ----
  bf16x8 qf[2];
  {
    const int qrow = qrow0 + l16;
    const u16* qp = Qb + (size_t)qrow * QN + h*64 + quad*8;
    union { bf16x8 v; u16 h8[8]; } lo, hi, cv, sv, olo, ohi;
    lo.v = *(const bf16x8*)qp;
    hi.v = *(const bf16x8*)(qp + 32);
    cv.v = *(const bf16x8*)(cosb + qrow*64 + quad*8);   // cos[d+32]==cos[d]
    sv.v = *(const bf16x8*)(sinb + qrow*64 + quad*8);
    #pragma unroll
    for (int j = 0; j < 8; j++) {
      const float x1 = bf2f(lo.h8[j]), x2 = bf2f(hi.h8[j]);
      const float c = bf2f(cv.h8[j]), sn = bf2f(sv.h8[j]);
      olo.h8[j] = f2bf((x1*c - x2*sn) * 0.125f);
      ohi.h8[j] = f2bf((x2*c + x1*sn) * 0.125f);
    }
    qf[0] = olo.v;
    qf[1] = ohi.v;
  }

  f32x4 oacc[4];
  #pragma unroll
  for (int nt = 0; nt < 4; nt++) oacc[nt] = (f32x4){0.f, 0.f, 0.f, 0.f};
  float m_run[4], l_run[4];
  #pragma unroll
  for (int r = 0; r < 4; r++) { m_run[r] = -1e30f; l_run[r] = 0.f; }

  const int sr = tid >> 3;          // 0..31
  const int sc = (tid & 7) * 8;     // 0..56

  // ---- register prefetch of tile 0 ----
  uint4 k0, k1, v0, v1;
  {
    k0 = *(const uint4*)(Kb + (size_t)(sr)      * KVNN + hkv*64 + sc);
    k1 = *(const uint4*)(Kb + (size_t)(sr + 32) * KVNN + hkv*64 + sc);
    v0 = *(const uint4*)(Vtg + (size_t)(hkv*64 + sr)      * SEQ + sc);
    v1 = *(const uint4*)(Vtg + (size_t)(hkv*64 + sr + 32) * SEQ + sc);
  }

  for (int kt = 0; kt < ktmax; kt++) {
    const int kb = kt * 64;
    const bool diag = (kt == qt);

    __syncthreads();                 // all waves done reading LDS (prev iter)
    *(uint4*)&Ks[sr][sc]      = k0;
    *(uint4*)&Ks[sr + 32][sc] = k1;
    *(uint4*)&Vt[sr][sc]      = v0;  // Vt row = d, col = key (pre-transposed)
    *(uint4*)&Vt[sr + 32][sc] = v1;
    __syncthreads();

    // ---- issue next tile's staging loads (latency hides behind compute) ----
    if (kt + 1 < ktmax) {
      const int kn = kb + 64;
      k0 = *(const uint4*)(Kb + (size_t)(kn + sr)      * KVNN + hkv*64 + sc);
      k1 = *(const uint4*)(Kb + (size_t)(kn + sr + 32) * KVNN + hkv*64 + sc);
      v0 = *(const uint4*)(Vtg + (size_t)(hkv*64 + sr)      * SEQ + kn + sc);
      v1 = *(const uint4*)(Vtg + (size_t)(hkv*64 + sr + 32) * SEQ + kn + sc);
    }

    // ---- S = Q @ K^T (skip fully-masked nt tiles on the diagonal) ----
    f32x4 sacc[4];
    #pragma unroll
    for (int nt = 0; nt < 4; nt++) sacc[nt] = (f32x4){0.f, 0.f, 0.f, 0.f};
    #pragma unroll
    for (int ks = 0; ks < 2; ks++)
      #pragma unroll
      for (int nt = 0; nt < 4; nt++)
        if (!diag || nt <= wave) {
          bf16x8 kf = *(const bf16x8*)&Ks[nt*16 + l16][ks*32 + quad*8];
          sacc[nt] = __builtin_amdgcn_mfma_f32_16x16x32_bf16(qf[ks], kf, sacc[nt], 0, 0, 0);
        }
    // ---- causal mask (diagonal tile only) ----
    if (diag) {
      #pragma unroll
      for (int nt = 0; nt < 4; nt++)
        #pragma unroll
        for (int r = 0; r < 4; r++)
          if (kb + nt*16 + l16 > qrow0 + quad*4 + r)
            sacc[nt][r] = -1e30f;
    }
    // ---- online softmax ----
    float alpha[4];
    #pragma unroll
    for (int r = 0; r < 4; r++) {
      float mx = fmaxf(fmaxf(sacc[0][r], sacc[1][r]), fmaxf(sacc[2][r], sacc[3][r]));
      mx = qmax16(mx);
      const float mnew = fmaxf(m_run[r], mx);
      alpha[r] = __expf(m_run[r] - mnew);
      m_run[r] = mnew;
      float rs = 0.f;
      #pragma unroll
      for (int nt = 0; nt < 4; nt++) {
        const float p = __expf(sacc[nt][r] - mnew);
        rs += p;
        Ps[wave][quad*4 + r][nt*16 + l16] = f2bf(p);   // C-layout write
      }
      rs = qsum16(rs);
      l_run[r] = l_run[r] * alpha[r] + rs;
    }
    #pragma unroll
    for (int nt = 0; nt < 4; nt++)
      #pragma unroll
      for (int r = 0; r < 4; r++)
        oacc[nt][r] *= alpha[r];
    // keep Ps vector loads below the scalar Ps stores (wave-private, in-order)
    asm volatile("" ::: "memory");
    // ---- O += P @ V (skip dead key-halves on the diagonal) ----
    #pragma unroll
    for (int ks = 0; ks < 2; ks++) {
      if (diag && wave < 2 && ks == 1) continue;  // keys 32..63 fully masked
      bf16x8 pf = *(const bf16x8*)&Ps[wave][l16][ks*32 + quad*8];
      #pragma unroll
      for (int nt = 0; nt < 4; nt++) {
        bf16x8 vf = *(const bf16x8*)&Vt[nt*16 + l16][ks*32 + quad*8];
        oacc[nt] = __builtin_amdgcn_mfma_f32_16x16x32_bf16(pf, vf, oacc[nt], 0, 0, 0);
      }
    }
  }

  // ---- epilogue ----
  #pragma unroll
  for (int r = 0; r < 4; r++) {
    const float inv = 1.0f / l_run[r];
    const int qrow = qrow0 + quad*4 + r;
    #pragma unroll
    for (int nt = 0; nt < 4; nt++)
      Ob[(size_t)qrow * QN + h*64 + nt*16 + l16] = f2bf(oacc[nt][r] * inv);
  }
}

// ---------------------------------------------------------------------------
extern "C" void kernel_launch(void* const* d_in, const int* in_sizes, int n_in,
                              void* d_out, int out_size, void* d_ws, size_t ws_size,
                              hipStream_t stream) {
  const void* X    = d_in[0];
  const void* cosr = d_in[1];
  const void* sinr = d_in[2];
  const void* wq   = d_in[3];
  const void* wk   = d_in[4];
  const void* wv   = d_in[5];
  const void* wo   = d_in[6];

  char* ws = (char*)d_ws;
  const size_t MB = 1024u * 1024u;
  u16* Xc   = (u16*)(ws);                      // 8 MB
  u16* wqc  = (u16*)(ws + 8*MB);               // 8 MB (Ab aliases after QKV gemm)
  u16* wkc  = (u16*)(ws + 16*MB);              // 2 MB
  u16* wvc  = (u16*)(ws + 18*MB);              // 2 MB
  u16* woc  = (u16*)(ws + 20*MB);              // 8 MB
  u16* cosc = (u16*)(ws + 28*MB);              // 256 KB
  u16* sinc = (u16*)(ws + 28*MB + 256*1024);   // 256 KB
  u16* Qb   = (u16*)(ws + 28*MB + 512*1024);   // 8 MB
  u16* Kb   = (u16*)(ws + 36*MB + 512*1024);   // 2 MB
  u16* Vb   = (u16*)(ws + 38*MB + 512*1024);   // 2 MB
  u16* Vtg  = (u16*)(ws + 40*MB + 512*1024);   // 2 MB
  u16* Ab   = wqc;   // wqc dead after gemm_qkv

  dim3 blk(256);
  conv_all<<<dim3(7296), blk, 0, stream>>>(X, cosr, sinr, wq, wk, wv, wo,
                                           Xc, cosc, sinc, wqc, wkc, wvc, woc);
  gemm_qkv<<<dim3(24, 32), blk, 0, stream>>>(Xc, wqc, wkc, wvc, Qb, Kb, Vb);
  rope_k<<<dim3((SEQ*NKVH*32)/256), blk, 0, stream>>>(Kb, cosc, sinc);
  vtrans<<<dim3(256), blk, 0, stream>>>(Vb, Vtg);
  attn_kernel<<<dim3(NQH, SEQ/64), blk, 0, stream>>>(Qb, Kb, Vtg, Ab, cosc, sinc);
  gemm_nt<<<dim3(16, 32), blk, 0, stream>>>(Ab, woc, d_out, SEQ, DMODEL, DMODEL,
                                            (const uint32_t*)cosr);
}